// Round 5
// baseline (2275.216 us; speedup 1.0000x reference)
//
#include <hip/hip_runtime.h>
#include <stdint.h>

typedef __attribute__((ext_vector_type(8))) _Float16 half8;
typedef __attribute__((ext_vector_type(2))) _Float16 half2v;
typedef __attribute__((ext_vector_type(4))) float floatx4;
typedef __attribute__((ext_vector_type(4))) uint32_t uint4v;

#define KDIM 4096
#define NDIM 11008
#define NKT 64  // K tiles of 64

#define GLOAD_LDS16(gsrc, ldst)                                                        \
  __builtin_amdgcn_global_load_lds(                                                    \
      (const __attribute__((address_space(1))) void*)(gsrc),                           \
      (__attribute__((address_space(3))) void*)(ldst), 16, 0, 0)

static __device__ __forceinline__ uint32_t pkrtz(float a, float b) {
  auto h = __builtin_amdgcn_cvt_pkrtz(a, b);  // exact: values fp16-representable
  return __builtin_bit_cast(uint32_t, h);
}

// int32 of 8 nibbles -> half8 of (q-8)/7.5*s, in k-order. Exact (q-8) via 0x6400 trick.
static __device__ __forceinline__ half8 dq8(uint32_t q, half2v ssv) {
  half2v off; off[0] = (_Float16)(-1032.0f); off[1] = (_Float16)(-1032.0f);
  const uint32_t a0 = (q & 0x000F000Fu) | 0x64006400u;
  const uint32_t a1 = ((q >> 4) & 0x000F000Fu) | 0x64006400u;
  const uint32_t a2 = ((q >> 8) & 0x000F000Fu) | 0x64006400u;
  const uint32_t a3 = ((q >> 12) & 0x000F000Fu) | 0x64006400u;
  const uint32_t p0 = __builtin_amdgcn_perm(a1, a0, 0x05040100u);  // {k0,k1}
  const uint32_t p1 = __builtin_amdgcn_perm(a3, a2, 0x05040100u);  // {k2,k3}
  const uint32_t p2 = __builtin_amdgcn_perm(a1, a0, 0x07060302u);  // {k4,k5}
  const uint32_t p3 = __builtin_amdgcn_perm(a3, a2, 0x07060302u);  // {k6,k7}
  uint4v u;
  u[0] = __builtin_bit_cast(uint32_t, (__builtin_bit_cast(half2v, p0) + off) * ssv);
  u[1] = __builtin_bit_cast(uint32_t, (__builtin_bit_cast(half2v, p1) + off) * ssv);
  u[2] = __builtin_bit_cast(uint32_t, (__builtin_bit_cast(half2v, p2) + off) * ssv);
  u[3] = __builtin_bit_cast(uint32_t, (__builtin_bit_cast(half2v, p3) + off) * ssv);
  return __builtin_bit_cast(half8, u);
}

// ---------------- prepass: fp32 -> fp16 copy of X into workspace ----------------
__global__ __launch_bounds__(256)
void l4b_prep(const float* __restrict__ in, _Float16* __restrict__ out, int n8) {
  int i = blockIdx.x * 256 + threadIdx.x;
  if (i < n8) {
    floatx4 v0 = ((const floatx4*)in)[2 * i];
    floatx4 v1 = ((const floatx4*)in)[2 * i + 1];
    uint4v u;
    u[0] = pkrtz(v0[0], v0[1]); u[1] = pkrtz(v0[2], v0[3]);
    u[2] = pkrtz(v1[0], v1[1]); u[3] = pkrtz(v1[2], v1[3]);
    ((uint4v*)out)[i] = u;
  }
}

// ---------------- main GEMM: 256x128 tile, A via gload_lds fp16, B in-reg ----------------
__global__ __launch_bounds__(512, 4)
void l4b_gemm256(const _Float16* __restrict__ XH,
                 const int* __restrict__ PW,
                 const float* __restrict__ SC,
                 float* __restrict__ OUT)
{
  // A tile [256 rows][64 halves] dbuf; row = 128B = 8 x 16B slots; content swizzled:
  // phys slot p holds logical slot p ^ (row&7). DMA writes linearly with pre-swizzled src.
  __shared__ alignas(16) _Float16 la[2][256 * 64];  // 64 KB

  const int tid  = threadIdx.x;
  const int lane = tid & 63;
  const int wave = tid >> 6;

  // XCD-aware swizzle (grid = 2752 = 8*344): consecutive wg on one XCD share A panel
  const int cpx = (int)gridDim.x >> 3;
  const int wg  = ((int)blockIdx.x & 7) * cpx + ((int)blockIdx.x >> 3);
  const int by  = wg / 86;
  const int bx  = wg - by * 86;
  const int64_t brow = (int64_t)by * 256;
  const int     bcol = bx * 128;

  // 4M x 2N wave grid, wave tile 64x64
  const int wr = (wave >> 1) * 64;
  const int wc = (wave & 1) * 64;
  const int fr = lane & 15;
  const int fq = lane >> 4;

  floatx4 acc[4][4];
#pragma unroll
  for (int i = 0; i < 4; ++i)
#pragma unroll
    for (int j = 0; j < 4; ++j) acc[i][j] = (floatx4)(0.0f);

  // A DMA: per wave 4 insts, inst g8 covers rows wave*32+g8*8 .. +7 (1 KB linear)
  const int arow8 = lane >> 3;            // row within 8-row group
  const int aslot = (lane & 7) ^ arow8;   // pre-swizzled source slot
  const _Float16* const asrc0 =
      XH + (brow + wave * 32 + arow8) * (int64_t)KDIM + aslot * 8;

  // B: lane's fragment (fn,ks) = one int32 at PW[kt*8 + ks*4 + fq][bcol+wc+fn*16+fr]
  const int ncol = bcol + wc + fr;
  const int*   const pwb = PW + (int64_t)fq * NDIM + ncol;
  const float* const scb = SC + ncol;

  int   rw0[8], rw1[8];
  float scc[4], scn[4];

#define DMA_A(t, b)                                                        \
  do {                                                                     \
    _Pragma("unroll") for (int g8 = 0; g8 < 4; ++g8)                       \
        GLOAD_LDS16(asrc0 + (int64_t)g8 * 8 * KDIM + (t) * 64,             \
                    &la[b][(wave * 32 + g8 * 8) * 64]);                    \
  } while (0)

#define LOADB(t, rw)                                                       \
  do {                                                                     \
    _Pragma("unroll") for (int k2 = 0; k2 < 2; ++k2)                       \
    _Pragma("unroll") for (int fn = 0; fn < 4; ++fn)                       \
        rw[k2 * 4 + fn] = pwb[((t) * 8 + k2 * 4) * NDIM + fn * 16];        \
  } while (0)

#define LOADSC(g, s)                                                       \
  do {                                                                     \
    _Pragma("unroll") for (int fn = 0; fn < 4; ++fn)                       \
        s[fn] = scb[(g) * NDIM + fn * 16];                                 \
  } while (0)

#define DRAIN_BAR()                                                        \
  do {                                                                     \
    __builtin_amdgcn_sched_barrier(0);                                     \
    asm volatile("s_waitcnt vmcnt(0) lgkmcnt(0)" ::: "memory");            \
    __builtin_amdgcn_s_barrier();                                          \
    __builtin_amdgcn_sched_barrier(0);                                     \
  } while (0)

#define KS_HALF(lap, rw, sc, ko, ro)                                       \
  do {                                                                     \
    half8 af[4], bf[4];                                                    \
    _Pragma("unroll") for (int fm = 0; fm < 4; ++fm) {                     \
      const int m = wr + fm * 16 + fr;                                     \
      af[fm] = *(const half8*)&(lap)[m * 64 + ((((ko) + fq) ^ (m & 7)) * 8)]; \
    }                                                                      \
    _Pragma("unroll") for (int fn = 0; fn < 4; ++fn) {                     \
      const _Float16 s_ = (_Float16)((sc)[fn] * (1.0f / 7.5f));            \
      half2v sv; sv[0] = s_; sv[1] = s_;                                   \
      bf[fn] = dq8((uint32_t)(rw)[(ro) + fn], sv);                         \
    }                                                                      \
    asm volatile("s_waitcnt lgkmcnt(0)" ::: "memory");                     \
    __builtin_amdgcn_sched_barrier(0);                                     \
    __builtin_amdgcn_s_setprio(1);                                         \
    _Pragma("unroll") for (int fm = 0; fm < 4; ++fm)                       \
    _Pragma("unroll") for (int fn = 0; fn < 4; ++fn)                       \
        acc[fm][fn] = __builtin_amdgcn_mfma_f32_16x16x32_f16(              \
            af[fm], bf[fn], acc[fm][fn], 0, 0, 0);                         \
    __builtin_amdgcn_s_setprio(0);                                         \
  } while (0)

  // prologue: stage kt=0
  DMA_A(0, 0);
  LOADB(0, rw0);
  LOADSC(0, scc);
  DRAIN_BAR();

  for (int g = 0; g < 32; ++g) {
    // even kt = 2g: compute la[0]/rw0, prefetch kt 2g+1 into la[1]/rw1
    DMA_A(2 * g + 1, 1);
    LOADB(2 * g + 1, rw1);
    {
      const _Float16* lap = la[0];
      KS_HALF(lap, rw0, scc, 0, 0);
      KS_HALF(lap, rw0, scc, 4, 4);
    }
    DRAIN_BAR();

    // odd kt = 2g+1: compute la[1]/rw1, prefetch kt 2g+2 into la[0]/rw0
    if (g < 31) {
      DMA_A(2 * g + 2, 0);
      LOADB(2 * g + 2, rw0);
      LOADSC(g + 1, scn);
    }
    {
      const _Float16* lap = la[1];
      KS_HALF(lap, rw1, scc, 0, 0);
      KS_HALF(lap, rw1, scc, 4, 4);
    }
    DRAIN_BAR();
    if (g < 31) {
      scc[0] = scn[0]; scc[1] = scn[1]; scc[2] = scn[2]; scc[3] = scn[3];
    }
  }

  // epilogue: C/D map col=lane&15, row=(lane>>4)*4+reg; fp32 out
#pragma unroll
  for (int fm = 0; fm < 4; ++fm)
#pragma unroll
    for (int fn = 0; fn < 4; ++fn)
#pragma unroll
      for (int r = 0; r < 4; ++r) {
        const int64_t row = brow + wr + fm * 16 + fq * 4 + r;
        const int     col = bcol + wc + fn * 16 + fr;
        OUT[row * NDIM + col] = acc[fm][fn][r];
      }
}

// ---------------- fallback (round-3 kernel, proven): used only if ws too small ----------------
__global__ __launch_bounds__(512, 2)
void l4b_fb(const float* __restrict__ X, const int* __restrict__ PW,
            const float* __restrict__ SC, float* __restrict__ OUT)
{
  __shared__ alignas(16) _Float16 fla[2][256 * 64];
  __shared__ alignas(16) _Float16 flb[2][256 * 64];

  const int tid  = threadIdx.x;
  const int lane = tid & 63;
  const int wave = tid >> 6;

  const int cpx = (int)gridDim.x >> 3;
  const int wg  = ((int)blockIdx.x & 7) * cpx + ((int)blockIdx.x >> 3);
  const int by  = wg / 43;
  const int bx  = wg - by * 43;
  const int64_t brow = (int64_t)by * 256;
  const int     bcol = bx * 256;

  const int wr = (wave >> 2) * 128;
  const int wc = (wave & 3) * 64;
  const int fr = lane & 15;
  const int fq = lane >> 4;

  floatx4 acc[8][4];
#pragma unroll
  for (int i = 0; i < 8; ++i)
#pragma unroll
    for (int j = 0; j < 4; ++j) acc[i][j] = (floatx4)(0.0f);

  const int ar = tid >> 1;
  const int ah = tid & 1;
  const float* const aptr = X + (brow + ar) * (int64_t)KDIM + ah * 32;
  const int bc  = tid & 255;
  const int bkq = tid >> 8;
  const int*   const pwcol = PW + bcol + bc;
  const float* const sccol = SC + bcol + bc;

  floatx4 ra[8];
  int     rwf[4];
  float   rsc;

#define F_LOAD_A(t)                                                        \
  do {                                                                     \
    const float* ap = aptr + (t) * 64;                                     \
    _Pragma("unroll") for (int i_ = 0; i_ < 8; ++i_)                       \
        ra[i_] = *(const floatx4*)(ap + i_ * 4);                           \
  } while (0)

#define F_LOAD_B(t)                                                        \
  do {                                                                     \
    const int* pp = pwcol + ((t) * 8 + bkq) * NDIM;                        \
    _Pragma("unroll") for (int j_ = 0; j_ < 4; ++j_)                       \
        rwf[j_] = pp[j_ * 2 * NDIM];                                       \
    rsc = sccol[(int64_t)((t) >> 1) * NDIM];                               \
  } while (0)

#define F_WRITE_A(dst)                                                     \
  do {                                                                     \
    _Pragma("unroll") for (int i2 = 0; i2 < 4; ++i2) {                     \
      uint4v u;                                                            \
      u[0] = pkrtz(ra[2 * i2][0], ra[2 * i2][1]);                          \
      u[1] = pkrtz(ra[2 * i2][2], ra[2 * i2][3]);                          \
      u[2] = pkrtz(ra[2 * i2 + 1][0], ra[2 * i2 + 1][1]);                  \
      u[3] = pkrtz(ra[2 * i2 + 1][2], ra[2 * i2 + 1][3]);                  \
      const int s_ = ah * 4 + i2;                                          \
      *(half8*)&(dst)[ar * 64 + ((s_ ^ (ar & 7)) * 8)] =                   \
          __builtin_bit_cast(half8, u);                                    \
    }                                                                      \
  } while (0)

#define F_WRITE_B(dst)                                                     \
  do {                                                                     \
    const _Float16 ssf = (_Float16)(rsc * (1.0f / 7.5f));                  \
    half2v sv; sv[0] = ssf; sv[1] = ssf;                                   \
    _Pragma("unroll") for (int j_ = 0; j_ < 4; ++j_) {                     \
      half8 v = dq8((uint32_t)rwf[j_], sv);                                \
      const int kp = bkq + 2 * j_;                                         \
      *(half8*)&(dst)[bc * 64 + ((kp ^ (bc & 7)) * 8)] = v;                \
    }                                                                      \
  } while (0)

#define F_MFMA16(fm0)                                                      \
  __builtin_amdgcn_s_barrier();                                            \
  asm volatile("s_waitcnt lgkmcnt(0)" ::: "memory");                       \
  __builtin_amdgcn_sched_barrier(0);                                       \
  __builtin_amdgcn_s_setprio(1);                                           \
  _Pragma("unroll") for (int fm_ = 0; fm_ < 4; ++fm_)                      \
  _Pragma("unroll") for (int fn_ = 0; fn_ < 4; ++fn_)                      \
      acc[(fm0) + fm_][fn_] = __builtin_amdgcn_mfma_f32_16x16x32_f16(      \
          af[fm_], bfr[fn_], acc[(fm0) + fm_][fn_], 0, 0, 0);              \
  __builtin_amdgcn_s_setprio(0);                                           \
  __builtin_amdgcn_sched_barrier(0);                                       \
  __builtin_amdgcn_s_barrier();                                            \
  __builtin_amdgcn_sched_barrier(0);

  F_LOAD_A(0); F_LOAD_B(0);
  F_WRITE_A(fla[0]); F_WRITE_B(flb[0]);
  F_LOAD_A(1); F_LOAD_B(1);
  asm volatile("s_waitcnt lgkmcnt(0)" ::: "memory");
  __builtin_amdgcn_s_barrier();
  __builtin_amdgcn_sched_barrier(0);

  for (int kt = 0; kt < NKT; ++kt) {
    const int buf = kt & 1;
    const _Float16* lap = fla[buf];
    const _Float16* lbp = flb[buf];
    _Float16* const lan = fla[buf ^ 1];
    _Float16* const lbn = flb[buf ^ 1];
    const bool haveW = (kt + 1 < NKT);
    const bool haveL = (kt + 2 < NKT);

    half8 bfr[4], af[4];

#pragma unroll
    for (int fn_ = 0; fn_ < 4; ++fn_) {
      const int n_ = wc + fn_ * 16 + fr;
      bfr[fn_] = *(const half8*)&lbp[n_ * 64 + ((fq ^ (n_ & 7)) * 8)];
    }
#pragma unroll
    for (int fm_ = 0; fm_ < 4; ++fm_) {
      const int m_ = wr + fm_ * 16 + fr;
      af[fm_] = *(const half8*)&lap[m_ * 64 + ((fq ^ (m_ & 7)) * 8)];
    }
    if (haveW) F_WRITE_A(lan);
    F_MFMA16(0);

#pragma unroll
    for (int fm_ = 0; fm_ < 4; ++fm_) {
      const int m_ = wr + (4 + fm_) * 16 + fr;
      af[fm_] = *(const half8*)&lap[m_ * 64 + ((fq ^ (m_ & 7)) * 8)];
    }
    if (haveL) F_LOAD_A(kt + 2);
    F_MFMA16(4);

#pragma unroll
    for (int fn_ = 0; fn_ < 4; ++fn_) {
      const int n_ = wc + fn_ * 16 + fr;
      bfr[fn_] = *(const half8*)&lbp[n_ * 64 + (((4 + fq) ^ (n_ & 7)) * 8)];
    }
#pragma unroll
    for (int fm_ = 0; fm_ < 4; ++fm_) {
      const int m_ = wr + fm_ * 16 + fr;
      af[fm_] = *(const half8*)&lap[m_ * 64 + (((4 + fq) ^ (m_ & 7)) * 8)];
    }
    if (haveW) F_WRITE_B(lbn);
    F_MFMA16(0);

#pragma unroll
    for (int fm_ = 0; fm_ < 4; ++fm_) {
      const int m_ = wr + (4 + fm_) * 16 + fr;
      af[fm_] = *(const half8*)&lap[m_ * 64 + (((4 + fq) ^ (m_ & 7)) * 8)];
    }
    if (haveL) F_LOAD_B(kt + 2);
    F_MFMA16(4);
  }

#pragma unroll
  for (int fm = 0; fm < 8; ++fm)
#pragma unroll
    for (int fn = 0; fn < 4; ++fn)
#pragma unroll
      for (int r = 0; r < 4; ++r) {
        const int64_t row = brow + wr + fm * 16 + fq * 4 + r;
        const int     col = bcol + wc + fn * 16 + fr;
        OUT[row * NDIM + col] = acc[fm][fn][r];
      }
}

extern "C" void kernel_launch(void* const* d_in, const int* in_sizes, int n_in,
                              void* d_out, int out_size, void* d_ws, size_t ws_size,
                              hipStream_t stream) {
  const float* X   = (const float*)d_in[0];
  const int*   PW  = (const int*)d_in[1];
  const float* SC  = (const float*)d_in[2];
  float*       OUT = (float*)d_out;

  const int    M     = in_sizes[0] / KDIM;            // 8192
  const size_t needH = (size_t)in_sizes[0] * 2;       // fp16 copy of X

  if (ws_size >= needH && (M % 256) == 0) {
    _Float16* XH = (_Float16*)d_ws;
    const int n8 = in_sizes[0] / 8;
    l4b_prep<<<(n8 + 255) / 256, 256, 0, stream>>>(X, XH, n8);
    const int grid = (M / 256) * (NDIM / 128);        // 32 * 86 = 2752
    l4b_gemm256<<<grid, 512, 0, stream>>>(XH, PW, SC, OUT);
  } else {
    const int grid = (M / 256) * (NDIM / 256);        // 32 * 43 = 1376
    l4b_fb<<<grid, 512, 0, stream>>>(X, PW, SC, OUT);
  }
}

// Round 6
// 850.326 us; speedup vs baseline: 2.6757x; 2.6757x over previous
//
#include <hip/hip_runtime.h>
#include <stdint.h>

typedef __attribute__((ext_vector_type(8))) _Float16 half8;
typedef __attribute__((ext_vector_type(2))) _Float16 half2v;
typedef __attribute__((ext_vector_type(4))) float floatx4;
typedef __attribute__((ext_vector_type(4))) uint32_t uint4v;

#define KDIM 4096
#define NDIM 11008
#define NKT 64

#define GLOAD_LDS16(gsrc, ldst)                                                        \
  __builtin_amdgcn_global_load_lds(                                                    \
      (const __attribute__((address_space(1))) void*)(gsrc),                           \
      (__attribute__((address_space(3))) void*)(ldst), 16, 0, 0)

static __device__ __forceinline__ uint32_t pkrtz(float a, float b) {
  auto h = __builtin_amdgcn_cvt_pkrtz(a, b);  // exact: values fp16-representable
  return __builtin_bit_cast(uint32_t, h);
}

// int32 of 8 nibbles -> half8 of (q-8)/7.5*s in k-order; exact (q-8) via 0x6400 trick.
static __device__ __forceinline__ half8 dq8(uint32_t q, half2v ssv) {
  half2v off; off[0] = (_Float16)(-1032.0f); off[1] = (_Float16)(-1032.0f);
  const uint32_t a0 = (q & 0x000F000Fu) | 0x64006400u;
  const uint32_t a1 = ((q >> 4) & 0x000F000Fu) | 0x64006400u;
  const uint32_t a2 = ((q >> 8) & 0x000F000Fu) | 0x64006400u;
  const uint32_t a3 = ((q >> 12) & 0x000F000Fu) | 0x64006400u;
  const uint32_t p0 = __builtin_amdgcn_perm(a1, a0, 0x05040100u);
  const uint32_t p1 = __builtin_amdgcn_perm(a3, a2, 0x05040100u);
  const uint32_t p2 = __builtin_amdgcn_perm(a1, a0, 0x07060302u);
  const uint32_t p3 = __builtin_amdgcn_perm(a3, a2, 0x07060302u);
  uint4v u;
  u[0] = __builtin_bit_cast(uint32_t, (__builtin_bit_cast(half2v, p0) + off) * ssv);
  u[1] = __builtin_bit_cast(uint32_t, (__builtin_bit_cast(half2v, p1) + off) * ssv);
  u[2] = __builtin_bit_cast(uint32_t, (__builtin_bit_cast(half2v, p2) + off) * ssv);
  u[3] = __builtin_bit_cast(uint32_t, (__builtin_bit_cast(half2v, p3) + off) * ssv);
  return __builtin_bit_cast(half8, u);
}

// ---------------- prepass: fp32 -> fp16 copy of X into workspace ----------------
__global__ __launch_bounds__(256)
void l4b_prep(const float* __restrict__ in, _Float16* __restrict__ out, int n8) {
  int i = blockIdx.x * 256 + threadIdx.x;
  if (i < n8) {
    floatx4 v0 = ((const floatx4*)in)[2 * i];
    floatx4 v1 = ((const floatx4*)in)[2 * i + 1];
    uint4v u;
    u[0] = pkrtz(v0[0], v0[1]); u[1] = pkrtz(v0[2], v0[3]);
    u[2] = pkrtz(v1[0], v1[1]); u[3] = pkrtz(v1[2], v1[3]);
    ((uint4v*)out)[i] = u;
  }
}

// ---------------- main: 256x256 tile, A via gload_lds DMA, B dequant->LDS ----------------
__global__ __launch_bounds__(512, 2)
void l4b_main(const _Float16* __restrict__ XH,
              const int* __restrict__ PW,
              const float* __restrict__ SC,
              float* __restrict__ OUT)
{
  // Row = 64 halves = 128B = 8 x 16B slots; phys slot p holds logical slot p ^ (row&7).
  // A: DMA writes linearly with pre-swizzled global source. B: swizzled ds_write_b128.
  __shared__ alignas(16) _Float16 la[2][256 * 64];  // 64 KB
  __shared__ alignas(16) _Float16 lb[2][256 * 64];  // 64 KB

  const int tid  = threadIdx.x;
  const int lane = tid & 63;
  const int wave = tid >> 6;

  // XCD-aware bijective swizzle (grid = 1376 = 8*172)
  const int cpx = (int)gridDim.x >> 3;
  const int wg  = ((int)blockIdx.x & 7) * cpx + ((int)blockIdx.x >> 3);
  const int by  = wg / 43;
  const int bx  = wg - by * 43;
  const int64_t brow = (int64_t)by * 256;
  const int     bcol = bx * 256;

  // 2M x 4N wave grid, wave tile 128x64
  const int wr = (wave >> 2) * 128;
  const int wc = (wave & 3) * 64;
  const int fr = lane & 15;
  const int fq = lane >> 4;

  floatx4 acc[8][4];
#pragma unroll
  for (int i = 0; i < 8; ++i)
#pragma unroll
    for (int j = 0; j < 4; ++j) acc[i][j] = (floatx4)(0.0f);

  // A DMA: per wave 4 insts; inst g8 writes rows wave*32+g8*8 .. +7 (1 KB linear dest)
  const int arow8 = lane >> 3;
  const int aslot = (lane & 7) ^ arow8;  // pre-swizzled source slot
  const _Float16* const asrc0 =
      XH + (brow + wave * 32 + arow8) * (int64_t)KDIM + aslot * 8;

  // B staging: thread -> (col = tid&255, kq = tid>>8); 4 int32 per kt
  const int bc  = tid & 255;
  const int bkq = tid >> 8;
  const int*   const pwcol = PW + bcol + bc;
  const float* const sccol = SC + bcol + bc;

  int   rw[4];
  float rsc;

#define DMA_A(t, b)                                                        \
  do {                                                                     \
    _Pragma("unroll") for (int g8 = 0; g8 < 4; ++g8)                       \
        GLOAD_LDS16(asrc0 + (int64_t)g8 * 8 * KDIM + (t) * 64,             \
                    &la[b][(wave * 32 + g8 * 8) * 64]);                    \
  } while (0)

#define LOADB(t)                                                           \
  do {                                                                     \
    const int* pp = pwcol + ((t) * 8 + bkq) * NDIM;                        \
    _Pragma("unroll") for (int j_ = 0; j_ < 4; ++j_)                       \
        rw[j_] = pp[j_ * 2 * NDIM];                                        \
    rsc = sccol[(int64_t)((t) >> 1) * NDIM];                               \
  } while (0)

#define WRITE_B(dst)                                                       \
  do {                                                                     \
    const _Float16 ss = (_Float16)(rsc * (1.0f / 7.5f));                   \
    half2v sv; sv[0] = ss; sv[1] = ss;                                     \
    _Pragma("unroll") for (int j_ = 0; j_ < 4; ++j_) {                     \
      half8 v = dq8((uint32_t)rw[j_], sv);                                 \
      const int kp = bkq + 2 * j_;                                         \
      *(half8*)&(dst)[bc * 64 + ((kp ^ (bc & 7)) * 8)] = v;                \
    }                                                                      \
  } while (0)

#define READ_B4(ksl)                                                       \
  _Pragma("unroll") for (int fn_ = 0; fn_ < 4; ++fn_) {                    \
    const int n_ = wc + fn_ * 16 + fr;                                     \
    bfr[fn_] = *(const half8*)&lbp[n_ * 64 + (((ksl) ^ (n_ & 7)) * 8)];    \
  }

#define READ_A4(fm0, ksl)                                                  \
  _Pragma("unroll") for (int fm_ = 0; fm_ < 4; ++fm_) {                    \
    const int m_ = wr + ((fm0) + fm_) * 16 + fr;                           \
    af[fm_] = *(const half8*)&lap[m_ * 64 + (((ksl) ^ (m_ & 7)) * 8)];     \
  }

#define MFMA16(fm0)                                                        \
  __builtin_amdgcn_s_setprio(1);                                           \
  _Pragma("unroll") for (int fm_ = 0; fm_ < 4; ++fm_)                      \
  _Pragma("unroll") for (int fn_ = 0; fn_ < 4; ++fn_)                      \
      acc[(fm0) + fm_][fn_] = __builtin_amdgcn_mfma_f32_16x16x32_f16(      \
          af[fm_], bfr[fn_], acc[(fm0) + fm_][fn_], 0, 0, 0);              \
  __builtin_amdgcn_s_setprio(0);

#define PH_BAR()                                                           \
  do {                                                                     \
    __builtin_amdgcn_sched_barrier(0);                                     \
    __builtin_amdgcn_s_barrier();                                          \
    __builtin_amdgcn_sched_barrier(0);                                     \
  } while (0)

  // ---- prologue: stage tile 0 ----
  LOADB(0);
  DMA_A(0, 0);
  WRITE_B(lb[0]);  // compiler-inserted vmcnt wait on rw (DMA stays in flight behind it)
  __builtin_amdgcn_sched_barrier(0);
  asm volatile("s_waitcnt vmcnt(0) lgkmcnt(0)" ::: "memory");
  __builtin_amdgcn_s_barrier();
  __builtin_amdgcn_sched_barrier(0);

  for (int kt = 0; kt < NKT; ++kt) {
    const int buf = kt & 1;
    const _Float16* lap = la[buf];
    const _Float16* lbp = lb[buf];
    _Float16* const lbn = lb[buf ^ 1];
    const bool havep = (kt + 1 < NKT);

    half8 af[4], bfr[4];

    // P1: reads {B ks0, A fm0-3 ks0} | issue ALL next-tile VMEM | MFMA q0
    READ_B4(fq);
    READ_A4(0, fq);
    if (havep) {
      LOADB(kt + 1);
      DMA_A(kt + 1, buf ^ 1);
    }
    PH_BAR();
    MFMA16(0);
    PH_BAR();

    // P2: reads {A fm4-7 ks0} | MFMA q1 (bfr from P1)
    READ_A4(4, fq);
    PH_BAR();
    MFMA16(4);
    PH_BAR();

    // P3: reads {B ks1, A fm0-3 ks1} | dequant + ds_write B(kt+1) | MFMA q2
    READ_B4(4 + fq);
    READ_A4(0, 4 + fq);
    if (havep) WRITE_B(lbn);
    PH_BAR();
    MFMA16(0);
    PH_BAR();

    // P4: reads {A fm4-7 ks1} | MFMA q3 | end-of-kt full drain + barrier
    READ_A4(4, 4 + fq);
    PH_BAR();
    MFMA16(4);
    __builtin_amdgcn_sched_barrier(0);
    asm volatile("s_waitcnt vmcnt(0) lgkmcnt(0)" ::: "memory");
    __builtin_amdgcn_s_barrier();
    __builtin_amdgcn_sched_barrier(0);
  }

  // ---- epilogue: C/D map col=lane&15, row=(lane>>4)*4+reg; fp32 out ----
#pragma unroll
  for (int fm = 0; fm < 8; ++fm)
#pragma unroll
    for (int fn = 0; fn < 4; ++fn)
#pragma unroll
      for (int r = 0; r < 4; ++r) {
        const int64_t row = brow + wr + fm * 16 + fq * 4 + r;
        const int     col = bcol + wc + fn * 16 + fr;
        OUT[row * NDIM + col] = acc[fm][fn][r];
      }
}

// ---------------- fallback (round-3 kernel, proven): only if ws too small ----------------
__global__ __launch_bounds__(512, 2)
void l4b_fb(const float* __restrict__ X, const int* __restrict__ PW,
            const float* __restrict__ SC, float* __restrict__ OUT)
{
  __shared__ alignas(16) _Float16 fla[2][256 * 64];
  __shared__ alignas(16) _Float16 flb[2][256 * 64];

  const int tid  = threadIdx.x;
  const int lane = tid & 63;
  const int wave = tid >> 6;

  const int cpx = (int)gridDim.x >> 3;
  const int wg  = ((int)blockIdx.x & 7) * cpx + ((int)blockIdx.x >> 3);
  const int by  = wg / 43;
  const int bx  = wg - by * 43;
  const int64_t brow = (int64_t)by * 256;
  const int     bcol = bx * 256;

  const int wr = (wave >> 2) * 128;
  const int wc = (wave & 3) * 64;
  const int fr = lane & 15;
  const int fq = lane >> 4;

  floatx4 acc[8][4];
#pragma unroll
  for (int i = 0; i < 8; ++i)
#pragma unroll
    for (int j = 0; j < 4; ++j) acc[i][j] = (floatx4)(0.0f);

  const int ar = tid >> 1;
  const int ah = tid & 1;
  const float* const aptr = X + (brow + ar) * (int64_t)KDIM + ah * 32;
  const int bc  = tid & 255;
  const int bkq = tid >> 8;
  const int*   const pwcol = PW + bcol + bc;
  const float* const sccol = SC + bcol + bc;

  floatx4 ra[8];
  int     rwf[4];
  float   rsc;

#define F_LOAD_A(t)                                                        \
  do {                                                                     \
    const float* ap = aptr + (t) * 64;                                     \
    _Pragma("unroll") for (int i_ = 0; i_ < 8; ++i_)                       \
        ra[i_] = *(const floatx4*)(ap + i_ * 4);                           \
  } while (0)

#define F_LOAD_B(t)                                                        \
  do {                                                                     \
    const int* pp = pwcol + ((t) * 8 + bkq) * NDIM;                        \
    _Pragma("unroll") for (int j_ = 0; j_ < 4; ++j_)                       \
        rwf[j_] = pp[j_ * 2 * NDIM];                                       \
    rsc = sccol[(int64_t)((t) >> 1) * NDIM];                               \
  } while (0)

#define F_WRITE_A(dst)                                                     \
  do {                                                                     \
    _Pragma("unroll") for (int i2 = 0; i2 < 4; ++i2) {                     \
      uint4v u;                                                            \
      u[0] = pkrtz(ra[2 * i2][0], ra[2 * i2][1]);                          \
      u[1] = pkrtz(ra[2 * i2][2], ra[2 * i2][3]);                          \
      u[2] = pkrtz(ra[2 * i2 + 1][0], ra[2 * i2 + 1][1]);                  \
      u[3] = pkrtz(ra[2 * i2 + 1][2], ra[2 * i2 + 1][3]);                  \
      const int s_ = ah * 4 + i2;                                          \
      *(half8*)&(dst)[ar * 64 + ((s_ ^ (ar & 7)) * 8)] =                   \
          __builtin_bit_cast(half8, u);                                    \
    }                                                                      \
  } while (0)

#define F_WRITE_B(dst)                                                     \
  do {                                                                     \
    const _Float16 ssf = (_Float16)(rsc * (1.0f / 7.5f));                  \
    half2v sv; sv[0] = ssf; sv[1] = ssf;                                   \
    _Pragma("unroll") for (int j_ = 0; j_ < 4; ++j_) {                     \
      half8 v = dq8((uint32_t)rwf[j_], sv);                                \
      const int kp = bkq + 2 * j_;                                         \
      *(half8*)&(dst)[bc * 64 + ((kp ^ (bc & 7)) * 8)] = v;                \
    }                                                                      \
  } while (0)

#define F_MFMA16(fm0)                                                      \
  __builtin_amdgcn_s_barrier();                                            \
  asm volatile("s_waitcnt lgkmcnt(0)" ::: "memory");                       \
  __builtin_amdgcn_sched_barrier(0);                                       \
  __builtin_amdgcn_s_setprio(1);                                           \
  _Pragma("unroll") for (int fm_ = 0; fm_ < 4; ++fm_)                      \
  _Pragma("unroll") for (int fn_ = 0; fn_ < 4; ++fn_)                      \
      acc[(fm0) + fm_][fn_] = __builtin_amdgcn_mfma_f32_16x16x32_f16(      \
          af[fm_], bfr[fn_], acc[(fm0) + fm_][fn_], 0, 0, 0);              \
  __builtin_amdgcn_s_setprio(0);                                           \
  __builtin_amdgcn_sched_barrier(0);                                       \
  __builtin_amdgcn_s_barrier();                                            \
  __builtin_amdgcn_sched_barrier(0);

  F_LOAD_A(0); F_LOAD_B(0);
  F_WRITE_A(fla[0]); F_WRITE_B(flb[0]);
  F_LOAD_A(1); F_LOAD_B(1);
  asm volatile("s_waitcnt lgkmcnt(0)" ::: "memory");
  __builtin_amdgcn_s_barrier();
  __builtin_amdgcn_sched_barrier(0);

  for (int kt = 0; kt < NKT; ++kt) {
    const int buf = kt & 1;
    const _Float16* lap = fla[buf];
    const _Float16* lbp = flb[buf];
    _Float16* const lan = fla[buf ^ 1];
    _Float16* const lbn = flb[buf ^ 1];
    const bool haveW = (kt + 1 < NKT);
    const bool haveL = (kt + 2 < NKT);

    half8 bfr[4], af[4];

#pragma unroll
    for (int fn_ = 0; fn_ < 4; ++fn_) {
      const int n_ = wc + fn_ * 16 + fr;
      bfr[fn_] = *(const half8*)&lbp[n_ * 64 + ((fq ^ (n_ & 7)) * 8)];
    }
#pragma unroll
    for (int fm_ = 0; fm_ < 4; ++fm_) {
      const int m_ = wr + fm_ * 16 + fr;
      af[fm_] = *(const half8*)&lap[m_ * 64 + ((fq ^ (m_ & 7)) * 8)];
    }
    if (haveW) F_WRITE_A(lan);
    F_MFMA16(0);

#pragma unroll
    for (int fm_ = 0; fm_ < 4; ++fm_) {
      const int m_ = wr + (4 + fm_) * 16 + fr;
      af[fm_] = *(const half8*)&lap[m_ * 64 + ((fq ^ (m_ & 7)) * 8)];
    }
    if (haveL) F_LOAD_A(kt + 2);
    F_MFMA16(4);

#pragma unroll
    for (int fn_ = 0; fn_ < 4; ++fn_) {
      const int n_ = wc + fn_ * 16 + fr;
      bfr[fn_] = *(const half8*)&lbp[n_ * 64 + (((4 + fq) ^ (n_ & 7)) * 8)];
    }
#pragma unroll
    for (int fm_ = 0; fm_ < 4; ++fm_) {
      const int m_ = wr + fm_ * 16 + fr;
      af[fm_] = *(const half8*)&lap[m_ * 64 + (((4 + fq) ^ (m_ & 7)) * 8)];
    }
    if (haveW) F_WRITE_B(lbn);
    F_MFMA16(0);

#pragma unroll
    for (int fm_ = 0; fm_ < 4; ++fm_) {
      const int m_ = wr + (4 + fm_) * 16 + fr;
      af[fm_] = *(const half8*)&lap[m_ * 64 + (((4 + fq) ^ (m_ & 7)) * 8)];
    }
    if (haveL) F_LOAD_B(kt + 2);
    F_MFMA16(4);
  }

#pragma unroll
  for (int fm = 0; fm < 8; ++fm)
#pragma unroll
    for (int fn = 0; fn < 4; ++fn)
#pragma unroll
      for (int r = 0; r < 4; ++r) {
        const int64_t row = brow + wr + fm * 16 + fq * 4 + r;
        const int     col = bcol + wc + fn * 16 + fr;
        OUT[row * NDIM + col] = acc[fm][fn][r];
      }
}

extern "C" void kernel_launch(void* const* d_in, const int* in_sizes, int n_in,
                              void* d_out, int out_size, void* d_ws, size_t ws_size,
                              hipStream_t stream) {
  const float* X   = (const float*)d_in[0];
  const int*   PW  = (const int*)d_in[1];
  const float* SC  = (const float*)d_in[2];
  float*       OUT = (float*)d_out;

  const int    M     = in_sizes[0] / KDIM;       // 8192
  const size_t needH = (size_t)in_sizes[0] * 2;  // fp16 copy of X
  const int    grid  = (M / 256) * (NDIM / 256); // 32 * 43 = 1376

  if (ws_size >= needH && (M % 256) == 0) {
    _Float16* XH = (_Float16*)d_ws;
    const int n8 = in_sizes[0] / 8;
    l4b_prep<<<(n8 + 255) / 256, 256, 0, stream>>>(X, XH, n8);
    l4b_main<<<grid, 512, 0, stream>>>(XH, PW, SC, OUT);
  } else {
    l4b_fb<<<grid, 512, 0, stream>>>(X, PW, SC, OUT);
  }
}